// Round 8
// baseline (65.943 us; speedup 1.0000x reference)
//
#include <hip/hip_runtime.h>
#include <math.h>

// Problem: x (64, 4096) f32, A (4096, 1024) f32.
// out[b,i] = max_k( x[b,i] * sigmoid(A[i,k]) )
//          = x[b,i] * sigmoid( x[b,i] >= 0 ? max_k A[i,k] : min_k A[i,k] )
// (sigmoid monotone increasing; scaling by a >=0 / <0 scalar selects the
//  max / min argument. Exact under FP rounding; +/-0 both take the hi branch
//  and yield +/-0, matching the reference.)
//
// Single fused dispatch: out[:, i] depends only on A[i, :] and x[:, i], so a
// block owning rows [r0, r0+16) computes those rows' stats in LDS and writes
// the full 64x16 output slab. 256 blocks (1/CU) x 512 threads (2 waves/SIMD).
// Compulsory traffic: 16 MB A + 1 MB x read, 1 MB out write (~2.9 us @ 6.3 TB/s).

#define BATCH          64
#define SIZE_IN        4096
#define SIZE_OUT       1024
#define ROWS_PER_BLOCK 16
#define BLOCK          512

__global__ __launch_bounds__(BLOCK) void fused_minmax_scale(
    const float* __restrict__ x,     // [BATCH][SIZE_IN]
    const float* __restrict__ A,     // [SIZE_IN][SIZE_OUT]
    float* __restrict__ out)         // [BATCH][SIZE_IN]
{
    __shared__ __align__(16) float s_hi[ROWS_PER_BLOCK];  // sigmoid(rowmax)
    __shared__ __align__(16) float s_lo[ROWS_PER_BLOCK];  // sigmoid(rowmin)

    const int wave = threadIdx.x >> 6;   // 0..7
    const int lane = threadIdx.x & 63;
    const int r0   = blockIdx.x * ROWS_PER_BLOCK;

    // ---- Prefetch phase-2 operand BEFORE the barrier so its HBM latency ----
    // hides under the A fetch + reduction (a global load cannot be hoisted
    // across __syncthreads by the compiler).
    // Thread t: b = t>>3 (0..63), li = (t&7)*2 — 8 consecutive lanes cover one
    // contiguous 64 B segment of batch row b.
    const int t  = threadIdx.x;
    const int b  = t >> 3;
    const int li = (t & 7) * 2;
    const size_t xoff = (size_t)b * SIZE_IN + r0 + li;
    const float2 xv = *reinterpret_cast<const float2*>(x + xoff);

    // ---- Phase 1: per-row min/max of A. 8 waves x 2 rows each = 16 rows. ----
    // Issue ALL loads first (8 dwordx4 in flight per wave; the block's whole
    // 64 KB slab), then reduce — one burst fetch, one latency wait.
    float4 v[2][4];
#pragma unroll
    for (int rr = 0; rr < 2; ++rr) {
        const int row = r0 + wave + rr * 8;
        const float4* __restrict__ Arow =
            reinterpret_cast<const float4*>(A + (size_t)row * SIZE_OUT);
#pragma unroll
        for (int j = 0; j < 4; ++j)
            v[rr][j] = Arow[j * 64 + lane];   // coalesced: 1 KB/wave/instr
    }

#pragma unroll
    for (int rr = 0; rr < 2; ++rr) {
        float mx = -INFINITY;
        float mn =  INFINITY;
#pragma unroll
        for (int j = 0; j < 4; ++j) {
            const float4 w = v[rr][j];
            mx = fmaxf(mx, fmaxf(fmaxf(w.x, w.y), fmaxf(w.z, w.w)));
            mn = fminf(mn, fminf(fminf(w.x, w.y), fminf(w.z, w.w)));
        }
        // 64-lane butterfly (wave = 64 on CDNA4). After the off=1 step every
        // lane holds the full-row result; compute sigmoid on all lanes (VALU
        // is idle anyway) and store without a long divergent tail.
#pragma unroll
        for (int off = 32; off > 0; off >>= 1) {
            mx = fmaxf(mx, __shfl_xor(mx, off));
            mn = fminf(mn, __shfl_xor(mn, off));
        }
        const float hi = 1.0f / (1.0f + expf(-mx));
        const float lo = 1.0f / (1.0f + expf(-mn));
        if (lane == 0) {
            const int lrow = wave + rr * 8;
            s_hi[lrow] = hi;
            s_lo[lrow] = lo;
        }
    }
    __syncthreads();

    // ---- Phase 2: 64x16 output slab, float2 per thread. --------------------
    // LDS reads are 2-way-aliased broadcasts (free per m136); x already in regs.
    const float hi0 = s_hi[li],     lo0 = s_lo[li];
    const float hi1 = s_hi[li + 1], lo1 = s_lo[li + 1];

    float2 o;
    o.x = xv.x * (xv.x >= 0.0f ? hi0 : lo0);
    o.y = xv.y * (xv.y >= 0.0f ? hi1 : lo1);
    *reinterpret_cast<float2*>(out + xoff) = o;
}

extern "C" void kernel_launch(void* const* d_in, const int* in_sizes, int n_in,
                              void* d_out, int out_size, void* d_ws, size_t ws_size,
                              hipStream_t stream) {
    const float* x = (const float*)d_in[0];   // (64, 4096)
    const float* A = (const float*)d_in[1];   // (4096, 1024)
    float* out = (float*)d_out;               // (64, 4096)

    fused_minmax_scale<<<SIZE_IN / ROWS_PER_BLOCK, BLOCK, 0, stream>>>(x, A, out);
}